// Round 1
// baseline (4000.045 us; speedup 1.0000x reference)
//
#include <hip/hip_runtime.h>
#include <float.h>

#define BB 8
#define NN 2048
#define KK 20
#define ROWS 4

static constexpr float BN_INV_F = 0.9999950000374997f;  // 1/sqrt(1+1e-5)

// ---------------- squared norms: xx[b][n] = sum_c x[b][c][n]^2 ----------------
__global__ void sqnorm_kernel(const float* __restrict__ x, float* __restrict__ xx, int C) {
    int t = blockIdx.x * blockDim.x + threadIdx.x;  // b*NN + n
    if (t >= BB * NN) return;
    int b = t / NN, n = t % NN;
    const float* xb = x + (size_t)b * C * NN + n;
    float s = 0.f;
    for (int c = 0; c < C; ++c) {
        float v = xb[(size_t)c * NN];
        s += v * v;
    }
    xx[t] = s;
}

// ---------------- kNN: top-K of pd[n][m] = 2*inner - xx[n] - xx[m] ----------------
__global__ __launch_bounds__(256) void knn_kernel(const float* __restrict__ x,
                                                  const float* __restrict__ xx,
                                                  int* __restrict__ idxout, int C) {
    __shared__ float ctr[ROWS][128];
    __shared__ float pdl[ROWS][NN];
    __shared__ float rv[256];
    __shared__ int   ri[256];

    int blk = blockIdx.x;
    int b = blk / (NN / ROWS);
    int rbase = (blk % (NN / ROWS)) * ROWS;
    int tid = threadIdx.x;
    const float* xb = x + (size_t)b * C * NN;

    for (int i = tid; i < ROWS * C; i += 256) {
        int r = i / C, c = i % C;
        ctr[r][c] = xb[(size_t)c * NN + rbase + r];
    }
    __syncthreads();

    float xxn[ROWS];
    for (int r = 0; r < ROWS; ++r) xxn[r] = xx[b * NN + rbase + r];

    for (int chunk = 0; chunk < NN / 256; ++chunk) {
        int m = chunk * 256 + tid;
        float acc[ROWS];
        for (int r = 0; r < ROWS; ++r) acc[r] = 0.f;
        for (int c = 0; c < C; ++c) {
            float xv = xb[(size_t)c * NN + m];
            for (int r = 0; r < ROWS; ++r) acc[r] += ctr[r][c] * xv;
        }
        float xxm = xx[b * NN + m];
        for (int r = 0; r < ROWS; ++r)
            pdl[r][m] = 2.f * acc[r] - xxn[r] - xxm;
    }
    __syncthreads();

    // 20 serial argmax passes per row; tie-break = lowest index (lax.top_k)
    for (int r = 0; r < ROWS; ++r) {
        for (int k = 0; k < KK; ++k) {
            float bv = -FLT_MAX; int bi = NN;
            for (int m = tid; m < NN; m += 256) {
                float v = pdl[r][m];
                if (v > bv) { bv = v; bi = m; }   // ascending m: keeps lowest index on ties
            }
            rv[tid] = bv; ri[tid] = bi;
            __syncthreads();
            if (tid < 64) {
                float v = rv[tid]; int i0 = ri[tid];
                for (int j = 1; j < 4; ++j) {
                    float v2 = rv[tid + 64 * j]; int i2 = ri[tid + 64 * j];
                    if (v2 > v || (v2 == v && i2 < i0)) { v = v2; i0 = i2; }
                }
                for (int d = 32; d >= 1; d >>= 1) {
                    float v2 = __shfl_down(v, d, 64);
                    int   i2 = __shfl_down(i0, d, 64);
                    if (v2 > v || (v2 == v && i2 < i0)) { v = v2; i0 = i2; }
                }
                if (tid == 0) {
                    idxout[((size_t)(b * NN + rbase + r)) * KK + k] = i0;
                    pdl[r][i0] = -FLT_MAX;
                }
            }
            __syncthreads();
        }
    }
}

// ---------------- P/Q GEMM: Pt[b][n][o] = x[b][:,n]·w[o][0:C], Qt with w[o][C:2C] ----------------
__global__ __launch_bounds__(256) void pq_gemm_kernel(const float* __restrict__ x,
                                                      const float* __restrict__ w,
                                                      float* __restrict__ Pt, float* __restrict__ Qt,
                                                      int C, int Cout) {
    __shared__ float xt[128][64];
    int blk = blockIdx.x;
    int b = blk / (NN / 64);
    int nbase = (blk % (NN / 64)) * 64;
    int tid = threadIdx.x;
    const float* xb = x + (size_t)b * C * NN;

    for (int i = tid; i < C * 64; i += 256) {
        int c = i >> 6, j = i & 63;
        xt[c][j] = xb[(size_t)c * NN + nbase + j];
    }
    __syncthreads();

    int oi = tid & 3, j = tid >> 2;
    for (int obase = 0; obase < Cout; obase += 4) {
        int o = obase + oi;
        const float* wr = w + (size_t)o * 2 * C;
        float accP = 0.f, accQ = 0.f;
        for (int c = 0; c < C; ++c) {
            float xv = xt[c][j];
            accP += wr[c] * xv;
            accQ += wr[C + c] * xv;
        }
        size_t base = ((size_t)(b * NN + nbase + j)) * Cout + o;
        Pt[base] = accP;
        Qt[base] = accQ;
    }
}

// ---------------- edge max: out[b][o][n] = max_k leaky(g*BN_INV*(P[m_k]-P[n]+Q[n]) + b) ----------------
__global__ __launch_bounds__(256) void edge_max_kernel(const float* __restrict__ Pt,
                                                       const float* __restrict__ Qt,
                                                       const int* __restrict__ idx,
                                                       const float* __restrict__ g,
                                                       const float* __restrict__ bt,
                                                       float* __restrict__ out, int Cout) {
    __shared__ int lidx[16][KK];
    int blk = blockIdx.x;
    int b = blk / (NN / 16);
    int nbase = (blk % (NN / 16)) * 16;
    int tid = threadIdx.x;

    for (int i = tid; i < 16 * KK; i += 256) {
        int ns = i / KK, k = i % KK;
        lidx[ns][k] = idx[((size_t)(b * NN + nbase + ns)) * KK + k];
    }
    __syncthreads();

    int nsub = tid & 15, oi = tid >> 4;
    int n = nbase + nsub;
    for (int obase = 0; obase < Cout; obase += 16) {
        int o = obase + oi;
        size_t rowbase = ((size_t)(b * NN + n)) * Cout + o;
        float Pn = Pt[rowbase], Qn = Qt[rowbase];
        float off = Qn - Pn;
        float sc = g[o] * BN_INV_F;
        float bs = bt[o];
        float mx = -FLT_MAX;
        for (int k = 0; k < KK; ++k) {
            int m = lidx[nsub][k];
            float pv = Pt[((size_t)(b * NN + m)) * Cout + o];
            float h = pv + off;
            float y = sc * h + bs;
            y = (y >= 0.f) ? y : 0.2f * y;
            mx = fmaxf(mx, y);
        }
        out[((size_t)b * Cout + o) * NN + n] = mx;
    }
}

// ---------------- conv (wc, 1024x512) + BN + leaky + fused max/sum pooling ----------------
__global__ __launch_bounds__(256) void conv_pool_kernel(const float* __restrict__ x1, const float* __restrict__ x2,
                                                        const float* __restrict__ x3, const float* __restrict__ x4,
                                                        const float* __restrict__ wc, const float* __restrict__ gc,
                                                        const float* __restrict__ bc,
                                                        float* __restrict__ pmax, float* __restrict__ psum) {
    __shared__ float ft[512][16];
    int blk = blockIdx.x;          // blk = (b*64 + ot)*8 + ch
    int ch = blk & 7;
    int ot = (blk >> 3) & 63;
    int b  = blk >> 9;
    int tid = threadIdx.x;
    int nsub = tid & 15, oi = tid >> 4;
    int o = ot * 16 + oi;
    float sc = gc[o] * BN_INV_F, bs = bc[o];
    const float* wr = wc + (size_t)o * 512;
    float mx = -FLT_MAX, sm = 0.f;

    for (int nt = 0; nt < 16; ++nt) {
        int nb0 = ch * 256 + nt * 16;
        __syncthreads();
        for (int i = tid; i < 512 * 16; i += 256) {
            int c = i >> 4, j = i & 15;
            int n = nb0 + j;
            float v;
            if (c < 64)       v = x1[((size_t)b * 64  + c        ) * NN + n];
            else if (c < 128) v = x2[((size_t)b * 64  + (c - 64) ) * NN + n];
            else if (c < 256) v = x3[((size_t)b * 128 + (c - 128)) * NN + n];
            else              v = x4[((size_t)b * 256 + (c - 256)) * NN + n];
            ft[c][j] = v;
        }
        __syncthreads();
        float acc = 0.f;
        for (int c = 0; c < 512; ++c) acc += wr[c] * ft[c][nsub];
        float y = sc * acc + bs;
        y = (y >= 0.f) ? y : 0.2f * y;
        mx = fmaxf(mx, y);
        sm += y;
    }
    for (int d = 1; d < 16; d <<= 1) {
        float m2 = __shfl_xor(mx, d, 64);
        float s2 = __shfl_xor(sm, d, 64);
        mx = fmaxf(mx, m2);
        sm += s2;
    }
    if (nsub == 0) {
        pmax[((size_t)b * 1024 + o) * 8 + ch] = mx;
        psum[((size_t)b * 1024 + o) * 8 + ch] = sm;
    }
}

__global__ void pool_reduce_kernel(const float* __restrict__ pmax, const float* __restrict__ psum,
                                   float* __restrict__ x56) {
    int t = blockIdx.x * blockDim.x + threadIdx.x;
    if (t >= BB * 1024) return;
    int b = t / 1024, o = t % 1024;
    float mx = -FLT_MAX, sm = 0.f;
    for (int ch = 0; ch < 8; ++ch) {
        mx = fmaxf(mx, pmax[(size_t)t * 8 + ch]);
        sm += psum[(size_t)t * 8 + ch];
    }
    x56[(size_t)b * 2048 + o] = mx;
    x56[(size_t)b * 2048 + 1024 + o] = sm * (1.0f / 2048.0f);
}

// ---------------- FC: one wave per (b,o). mode0: leaky(g*dot*BNI+b); mode1: +bw inside; mode2: dot+bw ----------------
__global__ void fc_kernel(const float* __restrict__ in, const float* __restrict__ w,
                          const float* __restrict__ bw, const float* __restrict__ g,
                          const float* __restrict__ bt, float* __restrict__ out,
                          int Cin, int Cout, int mode) {
    int gt = blockIdx.x * blockDim.x + threadIdx.x;
    int wid = gt >> 6;
    int lane = threadIdx.x & 63;
    if (wid >= BB * Cout) return;
    int b = wid / Cout, o = wid % Cout;
    const float* ib = in + (size_t)b * Cin;
    const float* wr = w + (size_t)o * Cin;
    float acc = 0.f;
    for (int c = lane; c < Cin; c += 64) acc += ib[c] * wr[c];
    for (int d = 32; d >= 1; d >>= 1) acc += __shfl_down(acc, d, 64);
    if (lane == 0) {
        float y;
        if (mode == 0)      { y = g[o] * acc * BN_INV_F + bt[o]; y = (y >= 0.f) ? y : 0.2f * y; }
        else if (mode == 1) { float h = acc + bw[o]; y = g[o] * h * BN_INV_F + bt[o]; y = (y >= 0.f) ? y : 0.2f * y; }
        else                { y = acc + bw[o]; }
        out[(size_t)b * Cout + o] = y;
    }
}

extern "C" void kernel_launch(void* const* d_in, const int* in_sizes, int n_in,
                              void* d_out, int out_size, void* d_ws, size_t ws_size,
                              hipStream_t stream) {
    const float* x    = (const float*)d_in[0];
    const float* w1   = (const float*)d_in[1];
    const float* g1   = (const float*)d_in[2];
    const float* b1   = (const float*)d_in[3];
    const float* w2   = (const float*)d_in[4];
    const float* g2   = (const float*)d_in[5];
    const float* b2   = (const float*)d_in[6];
    const float* w3   = (const float*)d_in[7];
    const float* g3   = (const float*)d_in[8];
    const float* b3   = (const float*)d_in[9];
    const float* w4   = (const float*)d_in[10];
    const float* g4   = (const float*)d_in[11];
    const float* b4   = (const float*)d_in[12];
    const float* wc   = (const float*)d_in[13];
    const float* gc   = (const float*)d_in[14];
    const float* bc   = (const float*)d_in[15];
    const float* wf1  = (const float*)d_in[16];
    const float* gf1  = (const float*)d_in[17];
    const float* bf1  = (const float*)d_in[18];
    const float* wf2  = (const float*)d_in[19];
    const float* bwf2 = (const float*)d_in[20];
    const float* gf2  = (const float*)d_in[21];
    const float* bf2  = (const float*)d_in[22];
    const float* wf3  = (const float*)d_in[23];
    const float* bwf3 = (const float*)d_in[24];

    float* ws = (float*)d_ws;
    size_t off = 0;
    auto alloc = [&](size_t nfloats) {
        float* p = ws + off;
        off += (nfloats + 63) & ~(size_t)63;
        return p;
    };
    float* xx   = alloc((size_t)BB * NN);
    int*   idx  = (int*)alloc((size_t)BB * NN * KK);
    float* Pt   = alloc((size_t)BB * NN * 256);
    float* Qt   = alloc((size_t)BB * NN * 256);
    float* x1   = alloc((size_t)BB * 64 * NN);
    float* x2   = alloc((size_t)BB * 64 * NN);
    float* x3   = alloc((size_t)BB * 128 * NN);
    float* x4   = alloc((size_t)BB * 256 * NN);
    float* pmax = alloc((size_t)BB * 1024 * 8);
    float* psum = alloc((size_t)BB * 1024 * 8);
    float* x56  = alloc((size_t)BB * 2048);
    float* f1   = alloc((size_t)BB * 512);
    float* f2   = alloc((size_t)BB * 256);

    struct Layer { const float* xin; int C; const float* w; const float* g; const float* bt; float* xout; int Cout; };
    Layer L[4] = {
        { x,  3,   w1, g1, b1, x1, 64  },
        { x1, 64,  w2, g2, b2, x2, 64  },
        { x2, 64,  w3, g3, b3, x3, 128 },
        { x3, 128, w4, g4, b4, x4, 256 },
    };

    for (int l = 0; l < 4; ++l) {
        sqnorm_kernel<<<(BB * NN) / 256, 256, 0, stream>>>(L[l].xin, xx, L[l].C);
        knn_kernel<<<BB * (NN / ROWS), 256, 0, stream>>>(L[l].xin, xx, idx, L[l].C);
        pq_gemm_kernel<<<BB * (NN / 64), 256, 0, stream>>>(L[l].xin, L[l].w, Pt, Qt, L[l].C, L[l].Cout);
        edge_max_kernel<<<BB * (NN / 16), 256, 0, stream>>>(Pt, Qt, idx, L[l].g, L[l].bt, L[l].xout, L[l].Cout);
    }

    conv_pool_kernel<<<BB * 64 * 8, 256, 0, stream>>>(x1, x2, x3, x4, wc, gc, bc, pmax, psum);
    pool_reduce_kernel<<<(BB * 1024 + 255) / 256, 256, 0, stream>>>(pmax, psum, x56);
    fc_kernel<<<(BB * 512 * 64 + 255) / 256, 256, 0, stream>>>(x56, wf1, nullptr, gf1, bf1, f1, 2048, 512, 0);
    fc_kernel<<<(BB * 256 * 64 + 255) / 256, 256, 0, stream>>>(f1, wf2, bwf2, gf2, bf2, f2, 512, 256, 1);
    fc_kernel<<<(BB * 40 * 64 + 255) / 256, 256, 0, stream>>>(f2, wf3, bwf3, nullptr, nullptr, (float*)d_out, 256, 40, 2);
}

// Round 2
// 1155.096 us; speedup vs baseline: 3.4630x; 3.4630x over previous
//
#include <hip/hip_runtime.h>
#include <hip/hip_bf16.h>
#include <float.h>

#define BB 8
#define NN 2048
#define KK 20
#define KROWS 8

static constexpr float BN_INV_F = 0.9999950000374997f;  // 1/sqrt(1+1e-5)

typedef __attribute__((ext_vector_type(4))) float f32x4;
typedef __attribute__((ext_vector_type(8))) short s16x8;

__device__ __forceinline__ unsigned short f2bf(float f) {
    __hip_bfloat16 h = __float2bfloat16(f);
    return __builtin_bit_cast(unsigned short, h);
}
__device__ __forceinline__ float bf2f(unsigned short u) {
    unsigned int v = ((unsigned int)u) << 16;
    return __builtin_bit_cast(float, v);
}

// ---------------- split f32 -> bf16 hi/lo ----------------
__global__ void split_kernel(const float* __restrict__ w, unsigned short* __restrict__ hi,
                             unsigned short* __restrict__ lo, int n) {
    int t = blockIdx.x * blockDim.x + threadIdx.x;
    if (t >= n) return;
    float v = w[t];
    unsigned short h = f2bf(v);
    hi[t] = h;
    lo[t] = f2bf(v - bf2f(h));
}

// ---------------- squared norms: xx[b][n] = sum_c x[b][c][n]^2 ----------------
__global__ void sqnorm_kernel(const float* __restrict__ x, float* __restrict__ xx, int C) {
    int t = blockIdx.x * blockDim.x + threadIdx.x;
    if (t >= BB * NN) return;
    int b = t / NN, n = t % NN;
    const float* xb = x + (size_t)b * C * NN + n;
    float s = 0.f;
    for (int c = 0; c < C; ++c) {
        float v = xb[(size_t)c * NN];
        s += v * v;
    }
    xx[t] = s;
}

// ---------------- kNN: top-K of pd[n][m] = 2*inner - xx[n] - xx[m] ----------------
// 8 rows per block; pd phase: thread = 8 rows x 4 cols register block.
// top-k phase: 8 independent 32-lane groups, one row each, barrier-free.
__global__ __launch_bounds__(256) void knn_kernel(const float* __restrict__ x,
                                                  const float* __restrict__ xx,
                                                  int* __restrict__ idxout, int C) {
    __shared__ float pdl[KROWS][NN];      // 64 KB
    __shared__ float ctrT[128][KROWS];    // [c][r]
    __shared__ float xns[KROWS];

    int blk = blockIdx.x;
    int b = blk / (NN / KROWS);
    int rbase = (blk % (NN / KROWS)) * KROWS;
    int tid = threadIdx.x;
    const float* xb = x + (size_t)b * C * NN;

    for (int i = tid; i < C * KROWS; i += 256) {
        int c = i >> 3, r = i & 7;
        ctrT[c][r] = xb[(size_t)c * NN + rbase + r];
    }
    if (tid < KROWS) xns[tid] = xx[b * NN + rbase + tid];
    __syncthreads();

    for (int pass = 0; pass < 2; ++pass) {
        int m0 = pass * 1024 + tid * 4;
        float acc[KROWS][4];
        #pragma unroll
        for (int r = 0; r < KROWS; ++r)
            #pragma unroll
            for (int j = 0; j < 4; ++j) acc[r][j] = 0.f;

        for (int c = 0; c < C; ++c) {
            f32x4 xv = *(const f32x4*)(xb + (size_t)c * NN + m0);
            f32x4 c0 = *(const f32x4*)&ctrT[c][0];
            f32x4 c1 = *(const f32x4*)&ctrT[c][4];
            #pragma unroll
            for (int j = 0; j < 4; ++j) {
                acc[0][j] += c0.x * xv[j];
                acc[1][j] += c0.y * xv[j];
                acc[2][j] += c0.z * xv[j];
                acc[3][j] += c0.w * xv[j];
                acc[4][j] += c1.x * xv[j];
                acc[5][j] += c1.y * xv[j];
                acc[6][j] += c1.z * xv[j];
                acc[7][j] += c1.w * xv[j];
            }
        }
        f32x4 xm = *(const f32x4*)(xx + (size_t)b * NN + m0);
        #pragma unroll
        for (int r = 0; r < KROWS; ++r) {
            f32x4 out;
            #pragma unroll
            for (int j = 0; j < 4; ++j)
                out[j] = 2.f * acc[r][j] - xns[r] - xm[j];
            *(f32x4*)&pdl[r][m0] = out;
        }
    }
    __syncthreads();

    // top-K: group g (32 lanes) owns row g
    int g = tid >> 5, l32 = tid & 31;
    size_t rowglob = (size_t)b * NN + rbase + g;
    float* prow = pdl[g];
    for (int k = 0; k < KK; ++k) {
        float bv = -FLT_MAX; int bi = 0;
        #pragma unroll 4
        for (int i = 0; i < NN / 128; ++i) {      // 16 iters of b128
            int m = l32 * 4 + i * 128;
            f32x4 v = *(const f32x4*)&prow[m];
            #pragma unroll
            for (int j = 0; j < 4; ++j) {
                if (v[j] > bv) { bv = v[j]; bi = m + j; }
            }
        }
        #pragma unroll
        for (int d = 1; d < 32; d <<= 1) {
            float v2 = __shfl_xor(bv, d, 64);
            int   i2 = __shfl_xor(bi, d, 64);
            if (v2 > bv || (v2 == bv && i2 < bi)) { bv = v2; bi = i2; }
        }
        if (l32 == 0) idxout[rowglob * KK + k] = bi;
        prow[bi] = -FLT_MAX;   // all lanes, same addr/value; same-wave order guarantees visibility
    }
}

// ---------------- P/Q GEMM: Pt/Qt[b][n][o], register-blocked 8o x 4n ----------------
__global__ __launch_bounds__(256) void pq_gemm_kernel(const float* __restrict__ x,
                                                      const float* __restrict__ w,
                                                      float* __restrict__ Pt, float* __restrict__ Qt,
                                                      int C, int Cout) {
    __shared__ float wPT[128][8];
    __shared__ float wQT[128][8];
    int blk = blockIdx.x;            // ((b*(Cout/8)+og)*2 + pass)
    int pass = blk & 1;
    int rest = blk >> 1;
    int nog = Cout >> 3;
    int b = rest / nog;
    int obase = (rest % nog) * 8;
    int tid = threadIdx.x;
    const float* xb = x + (size_t)b * C * NN;

    for (int i = tid; i < C * 8; i += 256) {
        int c = i >> 3, r = i & 7;
        wPT[c][r] = w[(size_t)(obase + r) * 2 * C + c];
        wQT[c][r] = w[(size_t)(obase + r) * 2 * C + C + c];
    }
    __syncthreads();

    int m0 = pass * 1024 + tid * 4;
    float aP[8][4], aQ[8][4];
    #pragma unroll
    for (int r = 0; r < 8; ++r)
        #pragma unroll
        for (int j = 0; j < 4; ++j) { aP[r][j] = 0.f; aQ[r][j] = 0.f; }

    for (int c = 0; c < C; ++c) {
        f32x4 xv = *(const f32x4*)(xb + (size_t)c * NN + m0);
        f32x4 p0 = *(const f32x4*)&wPT[c][0];
        f32x4 p1 = *(const f32x4*)&wPT[c][4];
        f32x4 q0 = *(const f32x4*)&wQT[c][0];
        f32x4 q1 = *(const f32x4*)&wQT[c][4];
        #pragma unroll
        for (int j = 0; j < 4; ++j) {
            aP[0][j] += p0.x * xv[j]; aP[1][j] += p0.y * xv[j];
            aP[2][j] += p0.z * xv[j]; aP[3][j] += p0.w * xv[j];
            aP[4][j] += p1.x * xv[j]; aP[5][j] += p1.y * xv[j];
            aP[6][j] += p1.z * xv[j]; aP[7][j] += p1.w * xv[j];
            aQ[0][j] += q0.x * xv[j]; aQ[1][j] += q0.y * xv[j];
            aQ[2][j] += q0.z * xv[j]; aQ[3][j] += q0.w * xv[j];
            aQ[4][j] += q1.x * xv[j]; aQ[5][j] += q1.y * xv[j];
            aQ[6][j] += q1.z * xv[j]; aQ[7][j] += q1.w * xv[j];
        }
    }
    #pragma unroll
    for (int j = 0; j < 4; ++j) {
        size_t base = ((size_t)b * NN + m0 + j) * Cout + obase;
        f32x4 vP0, vP1, vQ0, vQ1;
        #pragma unroll
        for (int r = 0; r < 4; ++r) { vP0[r] = aP[r][j]; vP1[r] = aP[r + 4][j];
                                      vQ0[r] = aQ[r][j]; vQ1[r] = aQ[r + 4][j]; }
        *(f32x4*)&Pt[base] = vP0; *(f32x4*)&Pt[base + 4] = vP1;
        *(f32x4*)&Qt[base] = vQ0; *(f32x4*)&Qt[base + 4] = vQ1;
    }
}

// ---------------- edge max + feature emit (f32 [c][n] and bf16 hi/lo [n][c]) ----------------
__global__ __launch_bounds__(256) void edge_max_kernel(const float* __restrict__ Pt,
                                                       const float* __restrict__ Qt,
                                                       const int* __restrict__ idx,
                                                       const float* __restrict__ g,
                                                       const float* __restrict__ bt,
                                                       float* __restrict__ xf32,
                                                       unsigned short* __restrict__ Fhi,
                                                       unsigned short* __restrict__ Flo,
                                                       int coff, int Cout) {
    __shared__ int lidx[16][KK];
    int blk = blockIdx.x;
    int b = blk / (NN / 16);
    int nbase = (blk % (NN / 16)) * 16;
    int tid = threadIdx.x;

    for (int i = tid; i < 16 * KK; i += 256) {
        int ns = i / KK, k = i % KK;
        lidx[ns][k] = idx[((size_t)(b * NN + nbase + ns)) * KK + k];
    }
    __syncthreads();

    int oi = tid & 15, nsub = tid >> 4;
    int n = nbase + nsub;
    for (int obase = 0; obase < Cout; obase += 16) {
        int o = obase + oi;
        size_t rowbase = ((size_t)(b * NN + n)) * Cout + o;
        float Pn = Pt[rowbase], Qn = Qt[rowbase];
        float off = Qn - Pn;
        float sc = g[o] * BN_INV_F;
        float bs = bt[o];
        float mx = -FLT_MAX;
        #pragma unroll 4
        for (int k = 0; k < KK; ++k) {
            int m = lidx[nsub][k];
            float pv = Pt[((size_t)(b * NN + m)) * Cout + o];
            float y = sc * (pv + off) + bs;
            y = (y >= 0.f) ? y : 0.2f * y;
            mx = fmaxf(mx, y);
        }
        if (xf32) xf32[((size_t)b * Cout + o) * NN + n] = mx;
        size_t fb = ((size_t)b * NN + n) * 512 + coff + o;
        unsigned short h = f2bf(mx);
        Fhi[fb] = h;
        Flo[fb] = f2bf(mx - bf2f(h));
    }
}

// ---------------- conv (1024x512) via split-bf16 MFMA + fused pooling ----------------
// A = [Whi|Whi|Wlo] (K=1536), B = [Fhi;Flo;Fhi]. 128x128 tile, 4 waves.
__global__ __launch_bounds__(256) void conv_mfma_kernel(const unsigned short* __restrict__ Whi,
                                                        const unsigned short* __restrict__ Wlo,
                                                        const unsigned short* __restrict__ Fhi,
                                                        const unsigned short* __restrict__ Flo,
                                                        const float* __restrict__ gc,
                                                        const float* __restrict__ bc,
                                                        float* __restrict__ pmax,
                                                        float* __restrict__ psum) {
    __shared__ unsigned short As[128 * 64] __attribute__((aligned(16)));  // [o][k] swizzled
    __shared__ unsigned short Bs[128 * 64] __attribute__((aligned(16)));  // [n][k] swizzled

    int blk = blockIdx.x;             // b*128 + ot*16 + nt
    int nt = blk & 15, ot = (blk >> 4) & 7, b = blk >> 7;
    int obase = ot * 128, nbase = nt * 128;
    int tid = threadIdx.x, lane = tid & 63, wid = tid >> 6;
    int wo = wid >> 1, wn = wid & 1;

    f32x4 acc[4][4];
    #pragma unroll
    for (int m = 0; m < 4; ++m)
        #pragma unroll
        for (int q = 0; q < 4; ++q) acc[m][q] = (f32x4){0.f, 0.f, 0.f, 0.f};

    int srow = tid >> 1, sb = (tid & 1) * 4;

    for (int kt = 0; kt < 24; ++kt) {
        int seg = kt >> 3;
        int kc = (kt & 7) * 64;
        const unsigned short* Asrc = ((seg == 2) ? Wlo : Whi) + (size_t)obase * 512 + kc;
        const unsigned short* Bsrc = ((seg == 1) ? Flo : Fhi) + ((size_t)b * NN + nbase) * 512 + kc;
        __syncthreads();
        #pragma unroll
        for (int s = 0; s < 4; ++s) {
            int slot = sb + s;
            uint4 av = *(const uint4*)(Asrc + (size_t)srow * 512 + slot * 8);
            *(uint4*)(As + srow * 64 + ((slot ^ (srow & 7)) * 8)) = av;
            uint4 bv = *(const uint4*)(Bsrc + (size_t)srow * 512 + slot * 8);
            *(uint4*)(Bs + srow * 64 + ((slot ^ (srow & 7)) * 8)) = bv;
        }
        __syncthreads();
        #pragma unroll
        for (int ks = 0; ks < 2; ++ks) {
            s16x8 af[4], bf[4];
            #pragma unroll
            for (int m = 0; m < 4; ++m) {
                int r = wo * 64 + m * 16 + (lane & 15);
                int slot = (ks * 4 + (lane >> 4)) ^ (r & 7);
                af[m] = *(const s16x8*)(As + r * 64 + slot * 8);
                int r2 = wn * 64 + m * 16 + (lane & 15);
                int slot2 = (ks * 4 + (lane >> 4)) ^ (r2 & 7);
                bf[m] = *(const s16x8*)(Bs + r2 * 64 + slot2 * 8);
            }
            #pragma unroll
            for (int m = 0; m < 4; ++m)
                #pragma unroll
                for (int q = 0; q < 4; ++q)
                    acc[m][q] = __builtin_amdgcn_mfma_f32_16x16x32_bf16(af[m], bf[q], acc[m][q], 0, 0, 0);
        }
    }

    __syncthreads();
    float* redm = (float*)As;         // [wn*128 + olocal]
    float* reds = redm + 256;
    #pragma unroll
    for (int m = 0; m < 4; ++m) {
        #pragma unroll
        for (int rg = 0; rg < 4; ++rg) {
            int olocal = wo * 64 + m * 16 + (lane >> 4) * 4 + rg;
            int o = obase + olocal;
            float scv = gc[o] * BN_INV_F, bsv = bc[o];
            float mx = -FLT_MAX, sm = 0.f;
            #pragma unroll
            for (int q = 0; q < 4; ++q) {
                float y = scv * acc[m][q][rg] + bsv;
                y = (y >= 0.f) ? y : 0.2f * y;
                mx = fmaxf(mx, y);
                sm += y;
            }
            #pragma unroll
            for (int d = 1; d < 16; d <<= 1) {
                mx = fmaxf(mx, __shfl_xor(mx, d, 64));
                sm += __shfl_xor(sm, d, 64);
            }
            if ((lane & 15) == 0) {
                redm[wn * 128 + olocal] = mx;
                reds[wn * 128 + olocal] = sm;
            }
        }
    }
    __syncthreads();
    if (tid < 128) {
        float mx = fmaxf(redm[tid], redm[128 + tid]);
        float sm = reds[tid] + reds[128 + tid];
        size_t base = ((size_t)b * 1024 + obase + tid) * 16 + nt;
        pmax[base] = mx;
        psum[base] = sm;
    }
}

__global__ void pool_reduce_kernel(const float* __restrict__ pmax, const float* __restrict__ psum,
                                   float* __restrict__ x56) {
    int t = blockIdx.x * blockDim.x + threadIdx.x;
    if (t >= BB * 1024) return;
    int b = t >> 10, o = t & 1023;
    float mx = -FLT_MAX, sm = 0.f;
    for (int ch = 0; ch < 16; ++ch) {
        mx = fmaxf(mx, pmax[(size_t)t * 16 + ch]);
        sm += psum[(size_t)t * 16 + ch];
    }
    x56[(size_t)b * 2048 + o] = mx;
    x56[(size_t)b * 2048 + 1024 + o] = sm * (1.0f / 2048.0f);
}

// ---------------- FC: one wave per (b,o) ----------------
__global__ void fc_kernel(const float* __restrict__ in, const float* __restrict__ w,
                          const float* __restrict__ bw, const float* __restrict__ g,
                          const float* __restrict__ bt, float* __restrict__ out,
                          int Cin, int Cout, int mode) {
    int gt = blockIdx.x * blockDim.x + threadIdx.x;
    int wid = gt >> 6;
    int lane = threadIdx.x & 63;
    if (wid >= BB * Cout) return;
    int b = wid / Cout, o = wid % Cout;
    const float* ib = in + (size_t)b * Cin;
    const float* wr = w + (size_t)o * Cin;
    float acc = 0.f;
    for (int c = lane; c < Cin; c += 64) acc += ib[c] * wr[c];
    for (int d = 32; d >= 1; d >>= 1) acc += __shfl_down(acc, d, 64);
    if (lane == 0) {
        float y;
        if (mode == 0)      { y = g[o] * acc * BN_INV_F + bt[o]; y = (y >= 0.f) ? y : 0.2f * y; }
        else if (mode == 1) { float h = acc + bw[o]; y = g[o] * h * BN_INV_F + bt[o]; y = (y >= 0.f) ? y : 0.2f * y; }
        else                { y = acc + bw[o]; }
        out[(size_t)b * Cout + o] = y;
    }
}

extern "C" void kernel_launch(void* const* d_in, const int* in_sizes, int n_in,
                              void* d_out, int out_size, void* d_ws, size_t ws_size,
                              hipStream_t stream) {
    const float* x    = (const float*)d_in[0];
    const float* w1   = (const float*)d_in[1];
    const float* g1   = (const float*)d_in[2];
    const float* b1   = (const float*)d_in[3];
    const float* w2   = (const float*)d_in[4];
    const float* g2   = (const float*)d_in[5];
    const float* b2   = (const float*)d_in[6];
    const float* w3   = (const float*)d_in[7];
    const float* g3   = (const float*)d_in[8];
    const float* b3   = (const float*)d_in[9];
    const float* w4   = (const float*)d_in[10];
    const float* g4   = (const float*)d_in[11];
    const float* b4   = (const float*)d_in[12];
    const float* wc   = (const float*)d_in[13];
    const float* gc   = (const float*)d_in[14];
    const float* bc   = (const float*)d_in[15];
    const float* wf1  = (const float*)d_in[16];
    const float* gf1  = (const float*)d_in[17];
    const float* bf1  = (const float*)d_in[18];
    const float* wf2  = (const float*)d_in[19];
    const float* bwf2 = (const float*)d_in[20];
    const float* gf2  = (const float*)d_in[21];
    const float* bf2  = (const float*)d_in[22];
    const float* wf3  = (const float*)d_in[23];
    const float* bwf3 = (const float*)d_in[24];

    char* ws = (char*)d_ws;
    size_t off = 0;
    auto alloc = [&](size_t nbytes) {
        char* p = ws + off;
        off += (nbytes + 255) & ~(size_t)255;
        return p;
    };
    float* xx   = (float*)alloc((size_t)BB * NN * 4);
    int*   idx  = (int*)  alloc((size_t)BB * NN * KK * 4);
    float* Pt   = (float*)alloc((size_t)BB * NN * 256 * 4);
    float* Qt   = (float*)alloc((size_t)BB * NN * 256 * 4);
    float* x1   = (float*)alloc((size_t)BB * 64 * NN * 4);
    float* x2   = (float*)alloc((size_t)BB * 64 * NN * 4);
    float* x3   = (float*)alloc((size_t)BB * 128 * NN * 4);
    unsigned short* Fhi = (unsigned short*)alloc((size_t)BB * NN * 512 * 2);
    unsigned short* Flo = (unsigned short*)alloc((size_t)BB * NN * 512 * 2);
    unsigned short* Whi = (unsigned short*)alloc((size_t)1024 * 512 * 2);
    unsigned short* Wlo = (unsigned short*)alloc((size_t)1024 * 512 * 2);
    float* pmax = (float*)alloc((size_t)BB * 1024 * 16 * 4);
    float* psum = (float*)alloc((size_t)BB * 1024 * 16 * 4);
    float* x56  = (float*)alloc((size_t)BB * 2048 * 4);
    float* f1   = (float*)alloc((size_t)BB * 512 * 4);
    float* f2   = (float*)alloc((size_t)BB * 256 * 4);

    split_kernel<<<(1024 * 512 + 255) / 256, 256, 0, stream>>>(wc, Whi, Wlo, 1024 * 512);

    struct Layer { const float* xin; int C; const float* w; const float* g; const float* bt;
                   float* xout; int Cout; int coff; };
    Layer L[4] = {
        { x,  3,   w1, g1, b1, x1,      64,  0   },
        { x1, 64,  w2, g2, b2, x2,      64,  64  },
        { x2, 64,  w3, g3, b3, x3,      128, 128 },
        { x3, 128, w4, g4, b4, nullptr, 256, 256 },
    };

    for (int l = 0; l < 4; ++l) {
        sqnorm_kernel<<<(BB * NN) / 256, 256, 0, stream>>>(L[l].xin, xx, L[l].C);
        knn_kernel<<<BB * (NN / KROWS), 256, 0, stream>>>(L[l].xin, xx, idx, L[l].C);
        pq_gemm_kernel<<<BB * (L[l].Cout / 8) * 2, 256, 0, stream>>>(L[l].xin, L[l].w, Pt, Qt, L[l].C, L[l].Cout);
        edge_max_kernel<<<BB * (NN / 16), 256, 0, stream>>>(Pt, Qt, idx, L[l].g, L[l].bt,
                                                            L[l].xout, Fhi, Flo, L[l].coff, L[l].Cout);
    }

    conv_mfma_kernel<<<BB * 8 * 16, 256, 0, stream>>>(Whi, Wlo, Fhi, Flo, gc, bc, pmax, psum);
    pool_reduce_kernel<<<(BB * 1024 + 255) / 256, 256, 0, stream>>>(pmax, psum, x56);
    fc_kernel<<<(BB * 512 * 64 + 255) / 256, 256, 0, stream>>>(x56, wf1, nullptr, gf1, bf1, f1, 2048, 512, 0);
    fc_kernel<<<(BB * 256 * 64 + 255) / 256, 256, 0, stream>>>(f1, wf2, bwf2, gf2, bf2, f2, 512, 256, 1);
    fc_kernel<<<(BB * 40 * 64 + 255) / 256, 256, 0, stream>>>(f2, wf3, bwf3, nullptr, nullptr, (float*)d_out, 256, 40, 2);
}

// Round 3
// 1092.454 us; speedup vs baseline: 3.6615x; 1.0573x over previous
//
#include <hip/hip_runtime.h>
#include <hip/hip_bf16.h>
#include <float.h>

#define BB 8
#define NN 2048
#define KK 20
#define KROWS 8

static constexpr float BN_INV_F = 0.9999950000374997f;  // 1/sqrt(1+1e-5)

typedef __attribute__((ext_vector_type(4))) float f32x4;
typedef __attribute__((ext_vector_type(2))) float f32x2;
typedef __attribute__((ext_vector_type(8))) short s16x8;

__device__ __forceinline__ unsigned short f2bf(float f) {
    __hip_bfloat16 h = __float2bfloat16(f);
    return __builtin_bit_cast(unsigned short, h);
}
__device__ __forceinline__ float bf2f(unsigned short u) {
    unsigned int v = ((unsigned int)u) << 16;
    return __builtin_bit_cast(float, v);
}

// ---------------- split f32 -> bf16 hi/lo ----------------
__global__ void split_kernel(const float* __restrict__ w, unsigned short* __restrict__ hi,
                             unsigned short* __restrict__ lo, int n) {
    int t = blockIdx.x * blockDim.x + threadIdx.x;
    if (t >= n) return;
    float v = w[t];
    unsigned short h = f2bf(v);
    hi[t] = h;
    lo[t] = f2bf(v - bf2f(h));
}

// ---------------- squared norms: xx[b][n] = sum_c x[b][c][n]^2 ----------------
__global__ void sqnorm_kernel(const float* __restrict__ x, float* __restrict__ xx, int C) {
    int t = blockIdx.x * blockDim.x + threadIdx.x;
    if (t >= BB * NN) return;
    int b = t / NN, n = t % NN;
    const float* xb = x + (size_t)b * C * NN + n;
    float s = 0.f;
    for (int c = 0; c < C; ++c) {
        float v = xb[(size_t)c * NN];
        s += v * v;
    }
    xx[t] = s;
}

// ---------------- kNN: top-K of pd[n][m] = 2*inner - xx[n] - xx[m] ----------------
// pd phase: thread = 8 rows x 4 cols register block.
// top-k phase: tournament tree. 32-lane group per row; lane l caches max of its
// 64-elem chunk; per k: butterfly argmax over chunk-maxes -> rescan winning
// chunk only (96 elems touched per k instead of 2048).
__global__ __launch_bounds__(256) void knn_kernel(const float* __restrict__ x,
                                                  const float* __restrict__ xx,
                                                  int* __restrict__ idxout, int C) {
    __shared__ float pdl[KROWS][NN];      // 64 KB
    __shared__ float ctrT[128][KROWS];    // [c][r]
    __shared__ float xns[KROWS];

    int blk = blockIdx.x;
    int b = blk / (NN / KROWS);
    int rbase = (blk % (NN / KROWS)) * KROWS;
    int tid = threadIdx.x;
    const float* xb = x + (size_t)b * C * NN;

    for (int i = tid; i < C * KROWS; i += 256) {
        int c = i >> 3, r = i & 7;
        ctrT[c][r] = xb[(size_t)c * NN + rbase + r];
    }
    if (tid < KROWS) xns[tid] = xx[b * NN + rbase + tid];
    __syncthreads();

    for (int pass = 0; pass < 2; ++pass) {
        int m0 = pass * 1024 + tid * 4;
        float acc[KROWS][4];
        #pragma unroll
        for (int r = 0; r < KROWS; ++r)
            #pragma unroll
            for (int j = 0; j < 4; ++j) acc[r][j] = 0.f;

        for (int c = 0; c < C; ++c) {
            f32x4 xv = *(const f32x4*)(xb + (size_t)c * NN + m0);
            f32x4 c0 = *(const f32x4*)&ctrT[c][0];
            f32x4 c1 = *(const f32x4*)&ctrT[c][4];
            #pragma unroll
            for (int j = 0; j < 4; ++j) {
                acc[0][j] += c0.x * xv[j];
                acc[1][j] += c0.y * xv[j];
                acc[2][j] += c0.z * xv[j];
                acc[3][j] += c0.w * xv[j];
                acc[4][j] += c1.x * xv[j];
                acc[5][j] += c1.y * xv[j];
                acc[6][j] += c1.z * xv[j];
                acc[7][j] += c1.w * xv[j];
            }
        }
        f32x4 xm = *(const f32x4*)(xx + (size_t)b * NN + m0);
        #pragma unroll
        for (int r = 0; r < KROWS; ++r) {
            f32x4 out;
            #pragma unroll
            for (int j = 0; j < 4; ++j)
                out[j] = 2.f * acc[r][j] - xns[r] - xm[j];
            *(f32x4*)&pdl[r][m0] = out;
        }
    }
    __syncthreads();

    // ---- tournament top-K: group g (32 lanes) owns row g ----
    int g = tid >> 5, l32 = tid & 31;
    size_t rowglob = (size_t)b * NN + rbase + g;
    float* prow = pdl[g];

    // build: lane l32 owns chunk [l32*64, l32*64+64); diagonal offset to avoid
    // the 32-way bank conflict of stride-64-word reads (4-way instead).
    float bm = -FLT_MAX;
    #pragma unroll
    for (int i = 0; i < 16; ++i) {
        int offw = ((i + l32) & 15) * 4;
        f32x4 v = *(const f32x4*)&prow[l32 * 64 + offw];
        bm = fmaxf(bm, fmaxf(fmaxf(v.x, v.y), fmaxf(v.z, v.w)));
    }

    for (int k = 0; k < KK; ++k) {
        // 1) argmax over 32 chunk maxes; tie -> lower lane (= lower indices)
        float v = bm; int wl = l32;
        #pragma unroll
        for (int d = 1; d < 32; d <<= 1) {
            float v2 = __shfl_xor(v, d, 64);
            int   w2 = __shfl_xor(wl, d, 64);
            if (v2 > v || (v2 == v && w2 < wl)) { v = v2; wl = w2; }
        }
        int base = wl * 64;
        // 2) cooperative rescan of winning chunk: 2 elems/lane (2-way bank = free)
        f32x2 e = *(const f32x2*)&prow[base + l32 * 2];
        float lv; int li;
        if (e.x >= e.y) { lv = e.x; li = base + l32 * 2; }
        else            { lv = e.y; li = base + l32 * 2 + 1; }
        #pragma unroll
        for (int d = 1; d < 32; d <<= 1) {
            float v2 = __shfl_xor(lv, d, 64);
            int   i2 = __shfl_xor(li, d, 64);
            if (v2 > lv || (v2 == lv && i2 < li)) { lv = v2; li = i2; }
        }
        if (l32 == 0) idxout[rowglob * KK + k] = li;
        // 3) invalidate + new chunk max (exclude li in-register)
        float m0v = (base + l32 * 2     == li) ? -FLT_MAX : e.x;
        float m1v = (base + l32 * 2 + 1 == li) ? -FLT_MAX : e.y;
        float nb = fmaxf(m0v, m1v);
        #pragma unroll
        for (int d = 1; d < 32; d <<= 1) nb = fmaxf(nb, __shfl_xor(nb, d, 64));
        if (l32 == ((li >> 1) & 31)) prow[li] = -FLT_MAX;
        __builtin_amdgcn_wave_barrier();   // keep compiler from sinking the write
        if (l32 == wl) bm = nb;
    }
}

// ---------------- P/Q GEMM: Pt/Qt[b][n][o], register-blocked 8o x 4n ----------------
__global__ __launch_bounds__(256) void pq_gemm_kernel(const float* __restrict__ x,
                                                      const float* __restrict__ w,
                                                      float* __restrict__ Pt, float* __restrict__ Qt,
                                                      int C, int Cout) {
    __shared__ float wPT[128][8];
    __shared__ float wQT[128][8];
    int blk = blockIdx.x;            // ((b*(Cout/8)+og)*2 + pass)
    int pass = blk & 1;
    int rest = blk >> 1;
    int nog = Cout >> 3;
    int b = rest / nog;
    int obase = (rest % nog) * 8;
    int tid = threadIdx.x;
    const float* xb = x + (size_t)b * C * NN;

    for (int i = tid; i < C * 8; i += 256) {
        int c = i >> 3, r = i & 7;
        wPT[c][r] = w[(size_t)(obase + r) * 2 * C + c];
        wQT[c][r] = w[(size_t)(obase + r) * 2 * C + C + c];
    }
    __syncthreads();

    int m0 = pass * 1024 + tid * 4;
    float aP[8][4], aQ[8][4];
    #pragma unroll
    for (int r = 0; r < 8; ++r)
        #pragma unroll
        for (int j = 0; j < 4; ++j) { aP[r][j] = 0.f; aQ[r][j] = 0.f; }

    for (int c = 0; c < C; ++c) {
        f32x4 xv = *(const f32x4*)(xb + (size_t)c * NN + m0);
        f32x4 p0 = *(const f32x4*)&wPT[c][0];
        f32x4 p1 = *(const f32x4*)&wPT[c][4];
        f32x4 q0 = *(const f32x4*)&wQT[c][0];
        f32x4 q1 = *(const f32x4*)&wQT[c][4];
        #pragma unroll
        for (int j = 0; j < 4; ++j) {
            aP[0][j] += p0.x * xv[j]; aP[1][j] += p0.y * xv[j];
            aP[2][j] += p0.z * xv[j]; aP[3][j] += p0.w * xv[j];
            aP[4][j] += p1.x * xv[j]; aP[5][j] += p1.y * xv[j];
            aP[6][j] += p1.z * xv[j]; aP[7][j] += p1.w * xv[j];
            aQ[0][j] += q0.x * xv[j]; aQ[1][j] += q0.y * xv[j];
            aQ[2][j] += q0.z * xv[j]; aQ[3][j] += q0.w * xv[j];
            aQ[4][j] += q1.x * xv[j]; aQ[5][j] += q1.y * xv[j];
            aQ[6][j] += q1.z * xv[j]; aQ[7][j] += q1.w * xv[j];
        }
    }
    #pragma unroll
    for (int j = 0; j < 4; ++j) {
        size_t base = ((size_t)b * NN + m0 + j) * Cout + obase;
        f32x4 vP0, vP1, vQ0, vQ1;
        #pragma unroll
        for (int r = 0; r < 4; ++r) { vP0[r] = aP[r][j]; vP1[r] = aP[r + 4][j];
                                      vQ0[r] = aQ[r][j]; vQ1[r] = aQ[r + 4][j]; }
        *(f32x4*)&Pt[base] = vP0; *(f32x4*)&Pt[base + 4] = vP1;
        *(f32x4*)&Qt[base] = vQ0; *(f32x4*)&Qt[base + 4] = vQ1;
    }
}

// ---------------- edge max + feature emit (f32 [c][n] and bf16 hi/lo [n][c]) ----------------
__global__ __launch_bounds__(256) void edge_max_kernel(const float* __restrict__ Pt,
                                                       const float* __restrict__ Qt,
                                                       const int* __restrict__ idx,
                                                       const float* __restrict__ g,
                                                       const float* __restrict__ bt,
                                                       float* __restrict__ xf32,
                                                       unsigned short* __restrict__ Fhi,
                                                       unsigned short* __restrict__ Flo,
                                                       int coff, int Cout) {
    __shared__ int lidx[16][KK];
    int blk = blockIdx.x;
    int b = blk / (NN / 16);
    int nbase = (blk % (NN / 16)) * 16;
    int tid = threadIdx.x;

    for (int i = tid; i < 16 * KK; i += 256) {
        int ns = i / KK, k = i % KK;
        lidx[ns][k] = idx[((size_t)(b * NN + nbase + ns)) * KK + k];
    }
    __syncthreads();

    int oi = tid & 15, nsub = tid >> 4;
    int n = nbase + nsub;
    for (int obase = 0; obase < Cout; obase += 16) {
        int o = obase + oi;
        size_t rowbase = ((size_t)(b * NN + n)) * Cout + o;
        float Pn = Pt[rowbase], Qn = Qt[rowbase];
        float off = Qn - Pn;
        float sc = g[o] * BN_INV_F;
        float bs = bt[o];
        float mx = -FLT_MAX;
        #pragma unroll 4
        for (int k = 0; k < KK; ++k) {
            int m = lidx[nsub][k];
            float pv = Pt[((size_t)(b * NN + m)) * Cout + o];
            float y = sc * (pv + off) + bs;
            y = (y >= 0.f) ? y : 0.2f * y;
            mx = fmaxf(mx, y);
        }
        if (xf32) xf32[((size_t)b * Cout + o) * NN + n] = mx;
        size_t fb = ((size_t)b * NN + n) * 512 + coff + o;
        unsigned short h = f2bf(mx);
        Fhi[fb] = h;
        Flo[fb] = f2bf(mx - bf2f(h));
    }
}

// ---------------- conv (1024x512) via split-bf16 MFMA + fused pooling ----------------
// A = [Whi|Whi|Wlo] (K=1536), B = [Fhi;Flo;Fhi]. 128x128 tile, 4 waves.
__global__ __launch_bounds__(256) void conv_mfma_kernel(const unsigned short* __restrict__ Whi,
                                                        const unsigned short* __restrict__ Wlo,
                                                        const unsigned short* __restrict__ Fhi,
                                                        const unsigned short* __restrict__ Flo,
                                                        const float* __restrict__ gc,
                                                        const float* __restrict__ bc,
                                                        float* __restrict__ pmax,
                                                        float* __restrict__ psum) {
    __shared__ unsigned short As[128 * 64] __attribute__((aligned(16)));  // [o][k] swizzled
    __shared__ unsigned short Bs[128 * 64] __attribute__((aligned(16)));  // [n][k] swizzled

    int blk = blockIdx.x;             // b*128 + ot*16 + nt
    int nt = blk & 15, ot = (blk >> 4) & 7, b = blk >> 7;
    int obase = ot * 128, nbase = nt * 128;
    int tid = threadIdx.x, lane = tid & 63, wid = tid >> 6;
    int wo = wid >> 1, wn = wid & 1;

    f32x4 acc[4][4];
    #pragma unroll
    for (int m = 0; m < 4; ++m)
        #pragma unroll
        for (int q = 0; q < 4; ++q) acc[m][q] = (f32x4){0.f, 0.f, 0.f, 0.f};

    int srow = tid >> 1, sb = (tid & 1) * 4;

    for (int kt = 0; kt < 24; ++kt) {
        int seg = kt >> 3;
        int kc = (kt & 7) * 64;
        const unsigned short* Asrc = ((seg == 2) ? Wlo : Whi) + (size_t)obase * 512 + kc;
        const unsigned short* Bsrc = ((seg == 1) ? Flo : Fhi) + ((size_t)b * NN + nbase) * 512 + kc;
        __syncthreads();
        #pragma unroll
        for (int s = 0; s < 4; ++s) {
            int slot = sb + s;
            uint4 av = *(const uint4*)(Asrc + (size_t)srow * 512 + slot * 8);
            *(uint4*)(As + srow * 64 + ((slot ^ (srow & 7)) * 8)) = av;
            uint4 bv = *(const uint4*)(Bsrc + (size_t)srow * 512 + slot * 8);
            *(uint4*)(Bs + srow * 64 + ((slot ^ (srow & 7)) * 8)) = bv;
        }
        __syncthreads();
        #pragma unroll
        for (int ks = 0; ks < 2; ++ks) {
            s16x8 af[4], bf[4];
            #pragma unroll
            for (int m = 0; m < 4; ++m) {
                int r = wo * 64 + m * 16 + (lane & 15);
                int slot = (ks * 4 + (lane >> 4)) ^ (r & 7);
                af[m] = *(const s16x8*)(As + r * 64 + slot * 8);
                int r2 = wn * 64 + m * 16 + (lane & 15);
                int slot2 = (ks * 4 + (lane >> 4)) ^ (r2 & 7);
                bf[m] = *(const s16x8*)(Bs + r2 * 64 + slot2 * 8);
            }
            #pragma unroll
            for (int m = 0; m < 4; ++m)
                #pragma unroll
                for (int q = 0; q < 4; ++q)
                    acc[m][q] = __builtin_amdgcn_mfma_f32_16x16x32_bf16(af[m], bf[q], acc[m][q], 0, 0, 0);
        }
    }

    __syncthreads();
    float* redm = (float*)As;         // [wn*128 + olocal]
    float* reds = redm + 256;
    #pragma unroll
    for (int m = 0; m < 4; ++m) {
        #pragma unroll
        for (int rg = 0; rg < 4; ++rg) {
            int olocal = wo * 64 + m * 16 + (lane >> 4) * 4 + rg;
            int o = obase + olocal;
            float scv = gc[o] * BN_INV_F, bsv = bc[o];
            float mx = -FLT_MAX, sm = 0.f;
            #pragma unroll
            for (int q = 0; q < 4; ++q) {
                float y = scv * acc[m][q][rg] + bsv;
                y = (y >= 0.f) ? y : 0.2f * y;
                mx = fmaxf(mx, y);
                sm += y;
            }
            #pragma unroll
            for (int d = 1; d < 16; d <<= 1) {
                mx = fmaxf(mx, __shfl_xor(mx, d, 64));
                sm += __shfl_xor(sm, d, 64);
            }
            if ((lane & 15) == 0) {
                redm[wn * 128 + olocal] = mx;
                reds[wn * 128 + olocal] = sm;
            }
        }
    }
    __syncthreads();
    if (tid < 128) {
        float mx = fmaxf(redm[tid], redm[128 + tid]);
        float sm = reds[tid] + reds[128 + tid];
        size_t base = ((size_t)b * 1024 + obase + tid) * 16 + nt;
        pmax[base] = mx;
        psum[base] = sm;
    }
}

__global__ void pool_reduce_kernel(const float* __restrict__ pmax, const float* __restrict__ psum,
                                   float* __restrict__ x56) {
    int t = blockIdx.x * blockDim.x + threadIdx.x;
    if (t >= BB * 1024) return;
    int b = t >> 10, o = t & 1023;
    float mx = -FLT_MAX, sm = 0.f;
    for (int ch = 0; ch < 16; ++ch) {
        mx = fmaxf(mx, pmax[(size_t)t * 16 + ch]);
        sm += psum[(size_t)t * 16 + ch];
    }
    x56[(size_t)b * 2048 + o] = mx;
    x56[(size_t)b * 2048 + 1024 + o] = sm * (1.0f / 2048.0f);
}

// ---------------- FC: one wave per (b,o) ----------------
__global__ void fc_kernel(const float* __restrict__ in, const float* __restrict__ w,
                          const float* __restrict__ bw, const float* __restrict__ g,
                          const float* __restrict__ bt, float* __restrict__ out,
                          int Cin, int Cout, int mode) {
    int gt = blockIdx.x * blockDim.x + threadIdx.x;
    int wid = gt >> 6;
    int lane = threadIdx.x & 63;
    if (wid >= BB * Cout) return;
    int b = wid / Cout, o = wid % Cout;
    const float* ib = in + (size_t)b * Cin;
    const float* wr = w + (size_t)o * Cin;
    float acc = 0.f;
    for (int c = lane; c < Cin; c += 64) acc += ib[c] * wr[c];
    for (int d = 32; d >= 1; d >>= 1) acc += __shfl_down(acc, d, 64);
    if (lane == 0) {
        float y;
        if (mode == 0)      { y = g[o] * acc * BN_INV_F + bt[o]; y = (y >= 0.f) ? y : 0.2f * y; }
        else if (mode == 1) { float h = acc + bw[o]; y = g[o] * h * BN_INV_F + bt[o]; y = (y >= 0.f) ? y : 0.2f * y; }
        else                { y = acc + bw[o]; }
        out[(size_t)b * Cout + o] = y;
    }
}

extern "C" void kernel_launch(void* const* d_in, const int* in_sizes, int n_in,
                              void* d_out, int out_size, void* d_ws, size_t ws_size,
                              hipStream_t stream) {
    const float* x    = (const float*)d_in[0];
    const float* w1   = (const float*)d_in[1];
    const float* g1   = (const float*)d_in[2];
    const float* b1   = (const float*)d_in[3];
    const float* w2   = (const float*)d_in[4];
    const float* g2   = (const float*)d_in[5];
    const float* b2   = (const float*)d_in[6];
    const float* w3   = (const float*)d_in[7];
    const float* g3   = (const float*)d_in[8];
    const float* b3   = (const float*)d_in[9];
    const float* w4   = (const float*)d_in[10];
    const float* g4   = (const float*)d_in[11];
    const float* b4   = (const float*)d_in[12];
    const float* wc   = (const float*)d_in[13];
    const float* gc   = (const float*)d_in[14];
    const float* bc   = (const float*)d_in[15];
    const float* wf1  = (const float*)d_in[16];
    const float* gf1  = (const float*)d_in[17];
    const float* bf1  = (const float*)d_in[18];
    const float* wf2  = (const float*)d_in[19];
    const float* bwf2 = (const float*)d_in[20];
    const float* gf2  = (const float*)d_in[21];
    const float* bf2  = (const float*)d_in[22];
    const float* wf3  = (const float*)d_in[23];
    const float* bwf3 = (const float*)d_in[24];

    char* ws = (char*)d_ws;
    size_t off = 0;
    auto alloc = [&](size_t nbytes) {
        char* p = ws + off;
        off += (nbytes + 255) & ~(size_t)255;
        return p;
    };
    float* xx   = (float*)alloc((size_t)BB * NN * 4);
    int*   idx  = (int*)  alloc((size_t)BB * NN * KK * 4);
    float* Pt   = (float*)alloc((size_t)BB * NN * 256 * 4);
    float* Qt   = (float*)alloc((size_t)BB * NN * 256 * 4);
    float* x1   = (float*)alloc((size_t)BB * 64 * NN * 4);
    float* x2   = (float*)alloc((size_t)BB * 64 * NN * 4);
    float* x3   = (float*)alloc((size_t)BB * 128 * NN * 4);
    unsigned short* Fhi = (unsigned short*)alloc((size_t)BB * NN * 512 * 2);
    unsigned short* Flo = (unsigned short*)alloc((size_t)BB * NN * 512 * 2);
    unsigned short* Whi = (unsigned short*)alloc((size_t)1024 * 512 * 2);
    unsigned short* Wlo = (unsigned short*)alloc((size_t)1024 * 512 * 2);
    float* pmax = (float*)alloc((size_t)BB * 1024 * 16 * 4);
    float* psum = (float*)alloc((size_t)BB * 1024 * 16 * 4);
    float* x56  = (float*)alloc((size_t)BB * 2048 * 4);
    float* f1   = (float*)alloc((size_t)BB * 512 * 4);
    float* f2   = (float*)alloc((size_t)BB * 256 * 4);

    split_kernel<<<(1024 * 512 + 255) / 256, 256, 0, stream>>>(wc, Whi, Wlo, 1024 * 512);

    struct Layer { const float* xin; int C; const float* w; const float* g; const float* bt;
                   float* xout; int Cout; int coff; };
    Layer L[4] = {
        { x,  3,   w1, g1, b1, x1,      64,  0   },
        { x1, 64,  w2, g2, b2, x2,      64,  64  },
        { x2, 64,  w3, g3, b3, x3,      128, 128 },
        { x3, 128, w4, g4, b4, nullptr, 256, 256 },
    };

    for (int l = 0; l < 4; ++l) {
        sqnorm_kernel<<<(BB * NN) / 256, 256, 0, stream>>>(L[l].xin, xx, L[l].C);
        knn_kernel<<<BB * (NN / KROWS), 256, 0, stream>>>(L[l].xin, xx, idx, L[l].C);
        pq_gemm_kernel<<<BB * (L[l].Cout / 8) * 2, 256, 0, stream>>>(L[l].xin, L[l].w, Pt, Qt, L[l].C, L[l].Cout);
        edge_max_kernel<<<BB * (NN / 16), 256, 0, stream>>>(Pt, Qt, idx, L[l].g, L[l].bt,
                                                            L[l].xout, Fhi, Flo, L[l].coff, L[l].Cout);
    }

    conv_mfma_kernel<<<BB * 8 * 16, 256, 0, stream>>>(Whi, Wlo, Fhi, Flo, gc, bc, pmax, psum);
    pool_reduce_kernel<<<(BB * 1024 + 255) / 256, 256, 0, stream>>>(pmax, psum, x56);
    fc_kernel<<<(BB * 512 * 64 + 255) / 256, 256, 0, stream>>>(x56, wf1, nullptr, gf1, bf1, f1, 2048, 512, 0);
    fc_kernel<<<(BB * 256 * 64 + 255) / 256, 256, 0, stream>>>(f1, wf2, bwf2, gf2, bf2, f2, 512, 256, 1);
    fc_kernel<<<(BB * 40 * 64 + 255) / 256, 256, 0, stream>>>(f2, wf3, bwf3, nullptr, nullptr, (float*)d_out, 256, 40, 2);
}

// Round 4
// 1074.094 us; speedup vs baseline: 3.7241x; 1.0171x over previous
//
#include <hip/hip_runtime.h>
#include <hip/hip_bf16.h>
#include <float.h>

#define BB 8
#define NN 2048
#define KK 20
#define KROWS 8
#define BROWS 4   // rows per extraction batch (pdl resident)

static constexpr float BN_INV_F = 0.9999950000374997f;  // 1/sqrt(1+1e-5)

typedef __attribute__((ext_vector_type(4))) float f32x4;
typedef __attribute__((ext_vector_type(2))) float f32x2;
typedef __attribute__((ext_vector_type(8))) short s16x8;

__device__ __forceinline__ unsigned short f2bf(float f) {
    __hip_bfloat16 h = __float2bfloat16(f);
    return __builtin_bit_cast(unsigned short, h);
}
__device__ __forceinline__ float bf2f(unsigned short u) {
    unsigned int v = ((unsigned int)u) << 16;
    return __builtin_bit_cast(float, v);
}

// ---------------- split f32 -> bf16 hi/lo ----------------
__global__ void split_kernel(const float* __restrict__ w, unsigned short* __restrict__ hi,
                             unsigned short* __restrict__ lo, int n) {
    int t = blockIdx.x * blockDim.x + threadIdx.x;
    if (t >= n) return;
    float v = w[t];
    unsigned short h = f2bf(v);
    hi[t] = h;
    lo[t] = f2bf(v - bf2f(h));
}

// ---------------- squared norms: xx[b][n] = sum_c x[b][c][n]^2 ----------------
__global__ void sqnorm_kernel(const float* __restrict__ x, float* __restrict__ xx, int C) {
    int t = blockIdx.x * blockDim.x + threadIdx.x;
    if (t >= BB * NN) return;
    int b = t / NN, n = t % NN;
    const float* xb = x + (size_t)b * C * NN + n;
    float s = 0.f;
    for (int c = 0; c < C; ++c) {
        float v = xb[(size_t)c * NN];
        s += v * v;
    }
    xx[t] = s;
}

// ---------------- kNN: top-K of pd[n][m] = 2*inner - xx[n] - xx[m] ----------------
// Block owns 8 rows, processed as 2 batches of 4 (pdl = 4 rows = 32 KB -> 4 blocks/CU).
// pd phase: thread = 4 rows x 4 cols register block, prefetch-depth-1 on global loads.
// top-k phase: tournament (chunk maxes in registers, rescan winning chunk only).
__global__ __launch_bounds__(256, 4) void knn_kernel(const float* __restrict__ x,
                                                     const float* __restrict__ xx,
                                                     int* __restrict__ idxout, int C) {
    __shared__ float pdl[BROWS][NN];      // 32 KB
    __shared__ float ctrT[128][KROWS];    // [c][r] for all 8 rows
    __shared__ float xns[KROWS];

    int blk = blockIdx.x;
    int b = blk / (NN / KROWS);
    int rbase = (blk % (NN / KROWS)) * KROWS;
    int tid = threadIdx.x;
    const float* xb = x + (size_t)b * C * NN;

    for (int i = tid; i < C * KROWS; i += 256) {
        int c = i >> 3, r = i & 7;
        ctrT[c][r] = xb[(size_t)c * NN + rbase + r];
    }
    if (tid < KROWS) xns[tid] = xx[b * NN + rbase + tid];
    __syncthreads();

    for (int bat = 0; bat < 2; ++bat) {
        // ---- pd phase: 4 rows x 2048 cols ----
        for (int pass = 0; pass < 2; ++pass) {
            int m0 = pass * 1024 + tid * 4;
            float acc[BROWS][4];
            #pragma unroll
            for (int r = 0; r < BROWS; ++r)
                #pragma unroll
                for (int j = 0; j < 4; ++j) acc[r][j] = 0.f;

            f32x4 xv = *(const f32x4*)(xb + m0);           // c = 0
            for (int c = 0; c + 1 < C; ++c) {
                f32x4 nxt = *(const f32x4*)(xb + (size_t)(c + 1) * NN + m0);
                f32x4 c0 = *(const f32x4*)&ctrT[c][bat * 4];
                #pragma unroll
                for (int j = 0; j < 4; ++j) {
                    acc[0][j] += c0.x * xv[j];
                    acc[1][j] += c0.y * xv[j];
                    acc[2][j] += c0.z * xv[j];
                    acc[3][j] += c0.w * xv[j];
                }
                xv = nxt;
            }
            {
                f32x4 c0 = *(const f32x4*)&ctrT[C - 1][bat * 4];
                #pragma unroll
                for (int j = 0; j < 4; ++j) {
                    acc[0][j] += c0.x * xv[j];
                    acc[1][j] += c0.y * xv[j];
                    acc[2][j] += c0.z * xv[j];
                    acc[3][j] += c0.w * xv[j];
                }
            }
            f32x4 xm = *(const f32x4*)(xx + (size_t)b * NN + m0);
            #pragma unroll
            for (int r = 0; r < BROWS; ++r) {
                f32x4 out;
                #pragma unroll
                for (int j = 0; j < 4; ++j)
                    out[j] = 2.f * acc[r][j] - xns[bat * 4 + r] - xm[j];
                *(f32x4*)&pdl[r][m0] = out;
            }
        }
        __syncthreads();

        // ---- tournament top-K: 4 groups of 32 lanes (tids 0..127) ----
        if (tid < 32 * BROWS) {
            int g = tid >> 5, l32 = tid & 31;
            size_t rowglob = (size_t)b * NN + rbase + bat * 4 + g;
            float* prow = pdl[g];

            float bm = -FLT_MAX;
            #pragma unroll
            for (int i = 0; i < 16; ++i) {
                int offw = ((i + l32) & 15) * 4;
                f32x4 v = *(const f32x4*)&prow[l32 * 64 + offw];
                bm = fmaxf(bm, fmaxf(fmaxf(v.x, v.y), fmaxf(v.z, v.w)));
            }

            for (int k = 0; k < KK; ++k) {
                float v = bm; int wl = l32;
                #pragma unroll
                for (int d = 1; d < 32; d <<= 1) {
                    float v2 = __shfl_xor(v, d, 64);
                    int   w2 = __shfl_xor(wl, d, 64);
                    if (v2 > v || (v2 == v && w2 < wl)) { v = v2; wl = w2; }
                }
                int base = wl * 64;
                f32x2 e = *(const f32x2*)&prow[base + l32 * 2];
                float lv; int li;
                if (e.x >= e.y) { lv = e.x; li = base + l32 * 2; }
                else            { lv = e.y; li = base + l32 * 2 + 1; }
                #pragma unroll
                for (int d = 1; d < 32; d <<= 1) {
                    float v2 = __shfl_xor(lv, d, 64);
                    int   i2 = __shfl_xor(li, d, 64);
                    if (v2 > lv || (v2 == lv && i2 < li)) { lv = v2; li = i2; }
                }
                if (l32 == 0) idxout[rowglob * KK + k] = li;
                float m0v = (base + l32 * 2     == li) ? -FLT_MAX : e.x;
                float m1v = (base + l32 * 2 + 1 == li) ? -FLT_MAX : e.y;
                float nb = fmaxf(m0v, m1v);
                #pragma unroll
                for (int d = 1; d < 32; d <<= 1) nb = fmaxf(nb, __shfl_xor(nb, d, 64));
                if (l32 == ((li >> 1) & 31)) prow[li] = -FLT_MAX;
                __builtin_amdgcn_wave_barrier();
                if (l32 == wl) bm = nb;
            }
        }
        __syncthreads();   // pdl reused by next batch
    }
}

// ---------------- P/Q GEMM: Pt/Qt[b][n][o], register-blocked 8o x 4n ----------------
__global__ __launch_bounds__(256) void pq_gemm_kernel(const float* __restrict__ x,
                                                      const float* __restrict__ w,
                                                      float* __restrict__ Pt, float* __restrict__ Qt,
                                                      int C, int Cout) {
    __shared__ float wPT[128][8];
    __shared__ float wQT[128][8];
    int blk = blockIdx.x;            // ((b*(Cout/8)+og)*2 + pass)
    int pass = blk & 1;
    int rest = blk >> 1;
    int nog = Cout >> 3;
    int b = rest / nog;
    int obase = (rest % nog) * 8;
    int tid = threadIdx.x;
    const float* xb = x + (size_t)b * C * NN;

    for (int i = tid; i < C * 8; i += 256) {
        int c = i >> 3, r = i & 7;
        wPT[c][r] = w[(size_t)(obase + r) * 2 * C + c];
        wQT[c][r] = w[(size_t)(obase + r) * 2 * C + C + c];
    }
    __syncthreads();

    int m0 = pass * 1024 + tid * 4;
    float aP[8][4], aQ[8][4];
    #pragma unroll
    for (int r = 0; r < 8; ++r)
        #pragma unroll
        for (int j = 0; j < 4; ++j) { aP[r][j] = 0.f; aQ[r][j] = 0.f; }

    for (int c = 0; c < C; ++c) {
        f32x4 xv = *(const f32x4*)(xb + (size_t)c * NN + m0);
        f32x4 p0 = *(const f32x4*)&wPT[c][0];
        f32x4 p1 = *(const f32x4*)&wPT[c][4];
        f32x4 q0 = *(const f32x4*)&wQT[c][0];
        f32x4 q1 = *(const f32x4*)&wQT[c][4];
        #pragma unroll
        for (int j = 0; j < 4; ++j) {
            aP[0][j] += p0.x * xv[j]; aP[1][j] += p0.y * xv[j];
            aP[2][j] += p0.z * xv[j]; aP[3][j] += p0.w * xv[j];
            aP[4][j] += p1.x * xv[j]; aP[5][j] += p1.y * xv[j];
            aP[6][j] += p1.z * xv[j]; aP[7][j] += p1.w * xv[j];
            aQ[0][j] += q0.x * xv[j]; aQ[1][j] += q0.y * xv[j];
            aQ[2][j] += q0.z * xv[j]; aQ[3][j] += q0.w * xv[j];
            aQ[4][j] += q1.x * xv[j]; aQ[5][j] += q1.y * xv[j];
            aQ[6][j] += q1.z * xv[j]; aQ[7][j] += q1.w * xv[j];
        }
    }
    #pragma unroll
    for (int j = 0; j < 4; ++j) {
        size_t base = ((size_t)b * NN + m0 + j) * Cout + obase;
        f32x4 vP0, vP1, vQ0, vQ1;
        #pragma unroll
        for (int r = 0; r < 4; ++r) { vP0[r] = aP[r][j]; vP1[r] = aP[r + 4][j];
                                      vQ0[r] = aQ[r][j]; vQ1[r] = aQ[r + 4][j]; }
        *(f32x4*)&Pt[base] = vP0; *(f32x4*)&Pt[base + 4] = vP1;
        *(f32x4*)&Qt[base] = vQ0; *(f32x4*)&Qt[base + 4] = vQ1;
    }
}

// ---------------- edge max + feature emit (f32 [c][n] and bf16 hi/lo [n][c]) ----------------
__global__ __launch_bounds__(256) void edge_max_kernel(const float* __restrict__ Pt,
                                                       const float* __restrict__ Qt,
                                                       const int* __restrict__ idx,
                                                       const float* __restrict__ g,
                                                       const float* __restrict__ bt,
                                                       float* __restrict__ xf32,
                                                       unsigned short* __restrict__ Fhi,
                                                       unsigned short* __restrict__ Flo,
                                                       int coff, int Cout) {
    __shared__ int lidx[16][KK];
    int blk = blockIdx.x;
    int b = blk / (NN / 16);
    int nbase = (blk % (NN / 16)) * 16;
    int tid = threadIdx.x;

    for (int i = tid; i < 16 * KK; i += 256) {
        int ns = i / KK, k = i % KK;
        lidx[ns][k] = idx[((size_t)(b * NN + nbase + ns)) * KK + k];
    }
    __syncthreads();

    int oi = tid & 15, nsub = tid >> 4;
    int n = nbase + nsub;
    for (int obase = 0; obase < Cout; obase += 16) {
        int o = obase + oi;
        size_t rowbase = ((size_t)(b * NN + n)) * Cout + o;
        float Pn = Pt[rowbase], Qn = Qt[rowbase];
        float off = Qn - Pn;
        float sc = g[o] * BN_INV_F;
        float bs = bt[o];
        float mx = -FLT_MAX;
        #pragma unroll 4
        for (int k = 0; k < KK; ++k) {
            int m = lidx[nsub][k];
            float pv = Pt[((size_t)(b * NN + m)) * Cout + o];
            float y = sc * (pv + off) + bs;
            y = (y >= 0.f) ? y : 0.2f * y;
            mx = fmaxf(mx, y);
        }
        if (xf32) xf32[((size_t)b * Cout + o) * NN + n] = mx;
        size_t fb = ((size_t)b * NN + n) * 512 + coff + o;
        unsigned short h = f2bf(mx);
        Fhi[fb] = h;
        Flo[fb] = f2bf(mx - bf2f(h));
    }
}

// ---------------- conv (1024x512) via split-bf16 MFMA + fused pooling ----------------
// A = [Whi|Whi|Wlo] (K=1536), B = [Fhi;Flo;Fhi]. 128x128 tile, 4 waves.
__global__ __launch_bounds__(256) void conv_mfma_kernel(const unsigned short* __restrict__ Whi,
                                                        const unsigned short* __restrict__ Wlo,
                                                        const unsigned short* __restrict__ Fhi,
                                                        const unsigned short* __restrict__ Flo,
                                                        const float* __restrict__ gc,
                                                        const float* __restrict__ bc,
                                                        float* __restrict__ pmax,
                                                        float* __restrict__ psum) {
    __shared__ unsigned short As[128 * 64] __attribute__((aligned(16)));  // [o][k] swizzled
    __shared__ unsigned short Bs[128 * 64] __attribute__((aligned(16)));  // [n][k] swizzled

    int blk = blockIdx.x;             // b*128 + ot*16 + nt
    int nt = blk & 15, ot = (blk >> 4) & 7, b = blk >> 7;
    int obase = ot * 128, nbase = nt * 128;
    int tid = threadIdx.x, lane = tid & 63, wid = tid >> 6;
    int wo = wid >> 1, wn = wid & 1;

    f32x4 acc[4][4];
    #pragma unroll
    for (int m = 0; m < 4; ++m)
        #pragma unroll
        for (int q = 0; q < 4; ++q) acc[m][q] = (f32x4){0.f, 0.f, 0.f, 0.f};

    int srow = tid >> 1, sb = (tid & 1) * 4;

    for (int kt = 0; kt < 24; ++kt) {
        int seg = kt >> 3;
        int kc = (kt & 7) * 64;
        const unsigned short* Asrc = ((seg == 2) ? Wlo : Whi) + (size_t)obase * 512 + kc;
        const unsigned short* Bsrc = ((seg == 1) ? Flo : Fhi) + ((size_t)b * NN + nbase) * 512 + kc;
        __syncthreads();
        #pragma unroll
        for (int s = 0; s < 4; ++s) {
            int slot = sb + s;
            uint4 av = *(const uint4*)(Asrc + (size_t)srow * 512 + slot * 8);
            *(uint4*)(As + srow * 64 + ((slot ^ (srow & 7)) * 8)) = av;
            uint4 bv = *(const uint4*)(Bsrc + (size_t)srow * 512 + slot * 8);
            *(uint4*)(Bs + srow * 64 + ((slot ^ (srow & 7)) * 8)) = bv;
        }
        __syncthreads();
        #pragma unroll
        for (int ks = 0; ks < 2; ++ks) {
            s16x8 af[4], bf[4];
            #pragma unroll
            for (int m = 0; m < 4; ++m) {
                int r = wo * 64 + m * 16 + (lane & 15);
                int slot = (ks * 4 + (lane >> 4)) ^ (r & 7);
                af[m] = *(const s16x8*)(As + r * 64 + slot * 8);
                int r2 = wn * 64 + m * 16 + (lane & 15);
                int slot2 = (ks * 4 + (lane >> 4)) ^ (r2 & 7);
                bf[m] = *(const s16x8*)(Bs + r2 * 64 + slot2 * 8);
            }
            #pragma unroll
            for (int m = 0; m < 4; ++m)
                #pragma unroll
                for (int q = 0; q < 4; ++q)
                    acc[m][q] = __builtin_amdgcn_mfma_f32_16x16x32_bf16(af[m], bf[q], acc[m][q], 0, 0, 0);
        }
    }

    __syncthreads();
    float* redm = (float*)As;         // [wn*128 + olocal]
    float* reds = redm + 256;
    #pragma unroll
    for (int m = 0; m < 4; ++m) {
        #pragma unroll
        for (int rg = 0; rg < 4; ++rg) {
            int olocal = wo * 64 + m * 16 + (lane >> 4) * 4 + rg;
            int o = obase + olocal;
            float scv = gc[o] * BN_INV_F, bsv = bc[o];
            float mx = -FLT_MAX, sm = 0.f;
            #pragma unroll
            for (int q = 0; q < 4; ++q) {
                float y = scv * acc[m][q][rg] + bsv;
                y = (y >= 0.f) ? y : 0.2f * y;
                mx = fmaxf(mx, y);
                sm += y;
            }
            #pragma unroll
            for (int d = 1; d < 16; d <<= 1) {
                mx = fmaxf(mx, __shfl_xor(mx, d, 64));
                sm += __shfl_xor(sm, d, 64);
            }
            if ((lane & 15) == 0) {
                redm[wn * 128 + olocal] = mx;
                reds[wn * 128 + olocal] = sm;
            }
        }
    }
    __syncthreads();
    if (tid < 128) {
        float mx = fmaxf(redm[tid], redm[128 + tid]);
        float sm = reds[tid] + reds[128 + tid];
        size_t base = ((size_t)b * 1024 + obase + tid) * 16 + nt;
        pmax[base] = mx;
        psum[base] = sm;
    }
}

__global__ void pool_reduce_kernel(const float* __restrict__ pmax, const float* __restrict__ psum,
                                   float* __restrict__ x56) {
    int t = blockIdx.x * blockDim.x + threadIdx.x;
    if (t >= BB * 1024) return;
    int b = t >> 10, o = t & 1023;
    float mx = -FLT_MAX, sm = 0.f;
    for (int ch = 0; ch < 16; ++ch) {
        mx = fmaxf(mx, pmax[(size_t)t * 16 + ch]);
        sm += psum[(size_t)t * 16 + ch];
    }
    x56[(size_t)b * 2048 + o] = mx;
    x56[(size_t)b * 2048 + 1024 + o] = sm * (1.0f / 2048.0f);
}

// ---------------- FC: one wave per (b,o) ----------------
__global__ void fc_kernel(const float* __restrict__ in, const float* __restrict__ w,
                          const float* __restrict__ bw, const float* __restrict__ g,
                          const float* __restrict__ bt, float* __restrict__ out,
                          int Cin, int Cout, int mode) {
    int gt = blockIdx.x * blockDim.x + threadIdx.x;
    int wid = gt >> 6;
    int lane = threadIdx.x & 63;
    if (wid >= BB * Cout) return;
    int b = wid / Cout, o = wid % Cout;
    const float* ib = in + (size_t)b * Cin;
    const float* wr = w + (size_t)o * Cin;
    float acc = 0.f;
    for (int c = lane; c < Cin; c += 64) acc += ib[c] * wr[c];
    for (int d = 32; d >= 1; d >>= 1) acc += __shfl_down(acc, d, 64);
    if (lane == 0) {
        float y;
        if (mode == 0)      { y = g[o] * acc * BN_INV_F + bt[o]; y = (y >= 0.f) ? y : 0.2f * y; }
        else if (mode == 1) { float h = acc + bw[o]; y = g[o] * h * BN_INV_F + bt[o]; y = (y >= 0.f) ? y : 0.2f * y; }
        else                { y = acc + bw[o]; }
        out[(size_t)b * Cout + o] = y;
    }
}

extern "C" void kernel_launch(void* const* d_in, const int* in_sizes, int n_in,
                              void* d_out, int out_size, void* d_ws, size_t ws_size,
                              hipStream_t stream) {
    const float* x    = (const float*)d_in[0];
    const float* w1   = (const float*)d_in[1];
    const float* g1   = (const float*)d_in[2];
    const float* b1   = (const float*)d_in[3];
    const float* w2   = (const float*)d_in[4];
    const float* g2   = (const float*)d_in[5];
    const float* b2   = (const float*)d_in[6];
    const float* w3   = (const float*)d_in[7];
    const float* g3   = (const float*)d_in[8];
    const float* b3   = (const float*)d_in[9];
    const float* w4   = (const float*)d_in[10];
    const float* g4   = (const float*)d_in[11];
    const float* b4   = (const float*)d_in[12];
    const float* wc   = (const float*)d_in[13];
    const float* gc   = (const float*)d_in[14];
    const float* bc   = (const float*)d_in[15];
    const float* wf1  = (const float*)d_in[16];
    const float* gf1  = (const float*)d_in[17];
    const float* bf1  = (const float*)d_in[18];
    const float* wf2  = (const float*)d_in[19];
    const float* bwf2 = (const float*)d_in[20];
    const float* gf2  = (const float*)d_in[21];
    const float* bf2  = (const float*)d_in[22];
    const float* wf3  = (const float*)d_in[23];
    const float* bwf3 = (const float*)d_in[24];

    char* ws = (char*)d_ws;
    size_t off = 0;
    auto alloc = [&](size_t nbytes) {
        char* p = ws + off;
        off += (nbytes + 255) & ~(size_t)255;
        return p;
    };
    float* xx   = (float*)alloc((size_t)BB * NN * 4);
    int*   idx  = (int*)  alloc((size_t)BB * NN * KK * 4);
    float* Pt   = (float*)alloc((size_t)BB * NN * 256 * 4);
    float* Qt   = (float*)alloc((size_t)BB * NN * 256 * 4);
    float* x1   = (float*)alloc((size_t)BB * 64 * NN * 4);
    float* x2   = (float*)alloc((size_t)BB * 64 * NN * 4);
    float* x3   = (float*)alloc((size_t)BB * 128 * NN * 4);
    unsigned short* Fhi = (unsigned short*)alloc((size_t)BB * NN * 512 * 2);
    unsigned short* Flo = (unsigned short*)alloc((size_t)BB * NN * 512 * 2);
    unsigned short* Whi = (unsigned short*)alloc((size_t)1024 * 512 * 2);
    unsigned short* Wlo = (unsigned short*)alloc((size_t)1024 * 512 * 2);
    float* pmax = (float*)alloc((size_t)BB * 1024 * 16 * 4);
    float* psum = (float*)alloc((size_t)BB * 1024 * 16 * 4);
    float* x56  = (float*)alloc((size_t)BB * 2048 * 4);
    float* f1   = (float*)alloc((size_t)BB * 512 * 4);
    float* f2   = (float*)alloc((size_t)BB * 256 * 4);

    split_kernel<<<(1024 * 512 + 255) / 256, 256, 0, stream>>>(wc, Whi, Wlo, 1024 * 512);

    struct Layer { const float* xin; int C; const float* w; const float* g; const float* bt;
                   float* xout; int Cout; int coff; };
    Layer L[4] = {
        { x,  3,   w1, g1, b1, x1,      64,  0   },
        { x1, 64,  w2, g2, b2, x2,      64,  64  },
        { x2, 64,  w3, g3, b3, x3,      128, 128 },
        { x3, 128, w4, g4, b4, nullptr, 256, 256 },
    };

    for (int l = 0; l < 4; ++l) {
        sqnorm_kernel<<<(BB * NN) / 256, 256, 0, stream>>>(L[l].xin, xx, L[l].C);
        knn_kernel<<<BB * (NN / KROWS), 256, 0, stream>>>(L[l].xin, xx, idx, L[l].C);
        pq_gemm_kernel<<<BB * (L[l].Cout / 8) * 2, 256, 0, stream>>>(L[l].xin, L[l].w, Pt, Qt, L[l].C, L[l].Cout);
        edge_max_kernel<<<BB * (NN / 16), 256, 0, stream>>>(Pt, Qt, idx, L[l].g, L[l].bt,
                                                            L[l].xout, Fhi, Flo, L[l].coff, L[l].Cout);
    }

    conv_mfma_kernel<<<BB * 8 * 16, 256, 0, stream>>>(Whi, Wlo, Fhi, Flo, gc, bc, pmax, psum);
    pool_reduce_kernel<<<(BB * 1024 + 255) / 256, 256, 0, stream>>>(pmax, psum, x56);
    fc_kernel<<<(BB * 512 * 64 + 255) / 256, 256, 0, stream>>>(x56, wf1, nullptr, gf1, bf1, f1, 2048, 512, 0);
    fc_kernel<<<(BB * 256 * 64 + 255) / 256, 256, 0, stream>>>(f1, wf2, bwf2, gf2, bf2, f2, 512, 256, 1);
    fc_kernel<<<(BB * 40 * 64 + 255) / 256, 256, 0, stream>>>(f2, wf3, bwf3, nullptr, nullptr, (float*)d_out, 256, 40, 2);
}